// Round 3
// baseline (1419.345 us; speedup 1.0000x reference)
//
#include <hip/hip_runtime.h>

// GC-LSTM (SMPL) — all-fp32 I/O per reference dtypes.
// Kernel 1: 1024 blocks x 256 thr, NBATCH=2 (ROWS=48), whole 48-step recurrence in LDS.
//   Per step: sparse-A aggregate -> 48x96x96 fp32 GEMM (6x3 reg tile) -> gates (c in regs).
// Kernel 2: projection [B*T,576] @ Wd^T + bd, LDS-tiled, K chunked by 96.
// seq scratch in d_ws: fp32 if ws_size allows (113 MB), else bf16 (56.6 MB).

#define TPB 256
#define ROWS 48
#define NBATCH 2

__device__ __forceinline__ float b2f(unsigned short u) {
    return __uint_as_float(((unsigned int)u) << 16);
}
__device__ __forceinline__ unsigned short f2b(float f) {
    unsigned int x = __float_as_uint(f);
    x = x + 0x7fffu + ((x >> 16) & 1u);   // RNE
    return (unsigned short)(x >> 16);
}
__device__ __forceinline__ float sigm(float x) {
    float t = __expf(-x);
    return 1.0f / (1.0f + t);
}
__device__ __forceinline__ float tanh_(float x) {
    float xc = fmaxf(x, -30.f);
    float t = __expf(-2.f * xc);
    return (1.f - t) / (1.f + t);
}

// LDS layout (kernel 1), total 55,808 B:
//   UG   float[96*48] @ 0      : planes 0-23 AX | 24-47 X | 48-71 Ah | 72-95 h;
//                                 after GEMM, same buffer holds G[n][row], n=gate*24+d
//   Wl   float[96*96] @ 18432  : combined weights W[k][n]
//   wgpf float[72]    @ 55296  : peephole weights
//   invd float[24]    @ 55584
//   nbr  s8[120]      @ 55680
template <int SEQF32>
__global__ void __launch_bounds__(TPB)
gclstm_main(const float* __restrict__ src,
            const float* __restrict__ tgt,
            const float* __restrict__ We,
            const float* __restrict__ be,
            const float* __restrict__ Wxl,
            const float* __restrict__ bxl,
            const float* __restrict__ Wxr,
            const float* __restrict__ Whl,
            const float* __restrict__ bhl,
            const float* __restrict__ Whr,
            const float* __restrict__ wg,
            const float* __restrict__ bg,
            float* __restrict__ seqf,
            unsigned short* __restrict__ seqh)
{
    extern __shared__ char smem[];
    float* UG = (float*)smem;
    float* Wl = (float*)(smem + 18432);
    float* wgpf = (float*)(smem + 55296);
    float* invd = (float*)(smem + 55584);
    signed char* nbr = (signed char*)(smem + 55680);

    const int tid = threadIdx.x;
    const int b0 = blockIdx.x * NBATCH;
    const int rg = tid & 7, cg = tid >> 3;     // 8 row-groups x 32 col-groups
    const int r0 = rg * 6, n0 = cg * 3;

    // ---- init: stage combined weights W[k][n] (fp32, exact) ----
    // k: 0..23 pairs AX with Wxl, 24..47 X with Wxr, 48..71 Ah with Whl, 72..95 h with Whr
    // n = gate*24 + d ; W[k][n] = w[gate][d][e], e = k % 24
    for (int i = tid; i < 9216; i += TPB) {
        int k = i / 96, n = i - k * 96;
        int g = n / 24, d = n - g * 24;
        int e = k % 24, sel = k / 24;
        const float* w = (sel == 0) ? Wxl : (sel == 1) ? Wxr : (sel == 2) ? Whl : Whr;
        Wl[i] = w[g * 576 + d * 24 + e];
    }
    if (tid < 72) wgpf[tid] = wg[tid];
    if (tid < 24) {
        const int par[24] = {-1,0,0,0,1,2,3,4,5,6,7,8,9,9,9,12,13,14,16,17,18,19,20,21};
        int j = tid, cnt = 0;
        signed char* rowp = nbr + j * 5;
        rowp[cnt++] = (signed char)j;
        int p = par[j];
        if (p >= 0) rowp[cnt++] = (signed char)p;
#pragma unroll
        for (int ch = 0; ch < 24; ++ch)
            if (par[ch] == j) rowp[cnt++] = (signed char)ch;
        for (int m = cnt; m < 5; ++m) rowp[m] = -1;
        invd[j] = 1.0f / (float)cnt;
    }

    // column bias (added in phase C): bias[n] = bxl[n] + bhl[n] + bg[n]
    float bias_r[3];
#pragma unroll
    for (int j = 0; j < 3; ++j)
        bias_r[j] = bxl[n0 + j] + bhl[n0 + j] + bg[n0 + j];

    // c state in registers: cell elems = 48 rows x 24 d = 1152; thread handles
    // idx = tid + q*256 for q<5 (guard idx<1152), r = idx%48, d = idx/48.
    float creg[5];
#pragma unroll
    for (int q = 0; q < 5; ++q) creg[q] = 0.f;

    // X0 = relu(enc(src[:, 0])) into planes 24-47; h=0 into planes 72-95
#pragma unroll
    for (int q = 0; q < 5; ++q) {
        int idx = tid + q * TPB;
        if (idx < 1152) {
            int r = idx % 48, d = idx / 48;
            int b = b0 + (r / 24), j = r % 24;
            const float* sp = src + (size_t)b * 1728 + j * 3;
            float x = be[d] + sp[0] * We[d * 3] + sp[1] * We[d * 3 + 1] + sp[2] * We[d * 3 + 2];
            UG[(24 + d) * 48 + r] = fmaxf(x, 0.f);
            UG[(72 + d) * 48 + r] = 0.f;
        }
    }
    __syncthreads();

    for (int s = 0; s < 48; ++s) {
        if (s == 24) {
            // decode phase: X = relu(enc(tgt[:, 0])), h/c carried
#pragma unroll
            for (int q = 0; q < 5; ++q) {
                int idx = tid + q * TPB;
                if (idx < 1152) {
                    int r = idx % 48, d = idx / 48;
                    int b = b0 + (r / 24), j = r % 24;
                    const float* tp = tgt + (size_t)b * 1728 + j * 3;
                    float x = be[d] + tp[0] * We[d * 3] + tp[1] * We[d * 3 + 1]
                            + tp[2] * We[d * 3 + 2];
                    UG[(24 + d) * 48 + r] = fmaxf(x, 0.f);
                }
            }
            __syncthreads();
        }

        // ---- phase A: planes 0-23 = A@X, planes 48-71 = A@h (2304 elems) ----
#pragma unroll
        for (int q = 0; q < 9; ++q) {
            int idx = tid + q * TPB;
            int r = idx % 48, t = idx / 48;      // t in 0..47
            int j = r % 24, bb = r - j;
            int e = (t < 24) ? t : (t - 24);
            int srcp = (t < 24) ? (24 + e) : (72 + e);
            int dstp = (t < 24) ? e : (48 + e);
            const float* P = UG + srcp * 48 + bb;
            float a = 0.f;
#pragma unroll
            for (int m = 0; m < 5; ++m) {
                int nb = nbr[j * 5 + m];
                if (nb >= 0) a += P[nb];
            }
            UG[dstp * 48 + r] = a * invd[j];
        }
        __syncthreads();

        // ---- phase B: GEMM G[row][n] = sum_k U[k][row] * W[k][n] ----
        float acc[6][3];
#pragma unroll
        for (int i = 0; i < 6; ++i)
#pragma unroll
            for (int j = 0; j < 3; ++j) acc[i][j] = 0.f;

#pragma unroll 4
        for (int k = 0; k < 96; ++k) {
            const float* up = UG + k * 48 + r0;
            float u0 = up[0], u1 = up[1], u2 = up[2];
            float u3 = up[3], u4 = up[4], u5 = up[5];
            const float* wp = Wl + k * 96 + n0;
            float w0 = wp[0], w1 = wp[1], w2 = wp[2];
            float u[6] = {u0, u1, u2, u3, u4, u5};
            float w[3] = {w0, w1, w2};
#pragma unroll
            for (int i = 0; i < 6; ++i)
#pragma unroll
                for (int j = 0; j < 3; ++j)
                    acc[i][j] = fmaf(u[i], w[j], acc[i][j]);
        }
        __syncthreads();   // all U reads done before G overwrites

        // ---- phase C: write G[n][row] (+bias) into UG ----
#pragma unroll
        for (int i = 0; i < 6; ++i)
#pragma unroll
            for (int j = 0; j < 3; ++j)
                UG[(n0 + j) * 48 + r0 + i] = acc[i][j] + bias_r[j];
        __syncthreads();

        // ---- phase D: gates / state; same-thread read-modify-write, no barrier inside ----
#pragma unroll
        for (int q = 0; q < 5; ++q) {
            int idx = tid + q * TPB;
            if (idx < 1152) {
                int r = idx % 48, d = idx / 48;
                float c = creg[q];
                float gi = UG[d * 48 + r];
                float gf = UG[(24 + d) * 48 + r];
                float gc = UG[(48 + d) * 48 + r];
                float go = UG[(72 + d) * 48 + r];
                float iv = sigm(fmaf(wgpf[d], c, gi));
                float fv = sigm(fmaf(wgpf[24 + d], c, gf));
                float cn = fmaf(fv, c, iv * tanh_(gc));
                float ov = sigm(fmaf(wgpf[48 + d], cn, go));
                creg[q] = cn;
                UG[(24 + d) * 48 + r] = ov;            // next X
                UG[(72 + d) * 48 + r] = ov * tanh_(cn); // next h
                if (s >= 24) {
                    size_t off = ((size_t)(b0 + r / 24) * 24 + (size_t)(s - 24)) * 576
                               + (size_t)(r % 24) * 24 + (size_t)d;
                    if (SEQF32) seqf[off] = ov;
                    else        seqh[off] = f2b(ov);
                }
            }
        }
        __syncthreads();
    }
}

// Kernel 2: out[row][o] = bd[o] + sum_k seq[row][k] * Wd[o][k], rows = B*T = 49152.
// 768 blocks x 192 thr, 64 rows/block, K chunked by 96.
// LDS: sq float[64*97] @ 0 (24,832 B), wd float[96*72] @ 24832 (27,648 B) => 52,480 B
template <int SEQF32>
__global__ void __launch_bounds__(192)
gclstm_proj(const float* __restrict__ seqf,
            const unsigned short* __restrict__ seqh,
            const float* __restrict__ Wd,
            const float* __restrict__ bd,
            float* __restrict__ out)
{
    extern __shared__ char smem[];
    float* sq = (float*)smem;
    float* wd = (float*)(smem + 24832);

    const int tid = threadIdx.x;
    const int R0 = blockIdx.x * 64;
    const int rg = tid % 16, cg = tid / 16;   // cg in 0..11
    const int rr = rg * 4, o0 = cg * 6;

    float acc[4][6];
#pragma unroll
    for (int i = 0; i < 4; ++i)
#pragma unroll
        for (int j = 0; j < 6; ++j) acc[i][j] = 0.f;

    for (int k0 = 0; k0 < 576; k0 += 96) {
        __syncthreads();
        for (int i = tid; i < 64 * 96; i += 192) {
            int r = i / 96, kk = i - r * 96;
            size_t gidx = (size_t)(R0 + r) * 576 + (size_t)(k0 + kk);
            sq[r * 97 + kk] = SEQF32 ? seqf[gidx] : b2f(seqh[gidx]);
        }
        for (int i = tid; i < 96 * 72; i += 192) {
            int kk = i / 72, o = i - kk * 72;
            wd[kk * 72 + o] = Wd[(size_t)o * 576 + (size_t)(k0 + kk)];
        }
        __syncthreads();
#pragma unroll 4
        for (int kk = 0; kk < 96; ++kk) {
            float ss[4];
#pragma unroll
            for (int i = 0; i < 4; ++i) ss[i] = sq[(rr + i) * 97 + kk];
            const float* wp = wd + kk * 72 + o0;
            float w[6] = {wp[0], wp[1], wp[2], wp[3], wp[4], wp[5]};
#pragma unroll
            for (int i = 0; i < 4; ++i)
#pragma unroll
                for (int j = 0; j < 6; ++j)
                    acc[i][j] = fmaf(ss[i], w[j], acc[i][j]);
        }
    }

#pragma unroll
    for (int j = 0; j < 6; ++j) {
        float bv = bd[o0 + j];
#pragma unroll
        for (int i = 0; i < 4; ++i)
            out[(size_t)(R0 + rr + i) * 72 + (size_t)(o0 + j)] = acc[i][j] + bv;
    }
}

extern "C" void kernel_launch(void* const* d_in, const int* in_sizes, int n_in,
                              void* d_out, int out_size, void* d_ws, size_t ws_size,
                              hipStream_t stream)
{
    const float* src = (const float*)d_in[0];
    const float* tgt = (const float*)d_in[1];
    const float* We  = (const float*)d_in[2];
    const float* be  = (const float*)d_in[3];
    const float* Wxl = (const float*)d_in[4];
    const float* bxl = (const float*)d_in[5];
    const float* Wxr = (const float*)d_in[6];
    const float* Whl = (const float*)d_in[7];
    const float* bhl = (const float*)d_in[8];
    const float* Whr = (const float*)d_in[9];
    const float* wg  = (const float*)d_in[10];
    const float* bg  = (const float*)d_in[11];
    const float* Wd  = (const float*)d_in[12];
    const float* bd  = (const float*)d_in[13];
    float* out = (float*)d_out;   // [2048][24][72] fp32

    const size_t seq_elems = (size_t)2048 * 24 * 576;
    if (ws_size >= seq_elems * 4) {
        float* seqf = (float*)d_ws;
        gclstm_main<1><<<dim3(1024), dim3(TPB), 55808, stream>>>(
            src, tgt, We, be, Wxl, bxl, Wxr, Whl, bhl, Whr, wg, bg, seqf, nullptr);
        gclstm_proj<1><<<dim3(768), dim3(192), 52480, stream>>>(seqf, nullptr, Wd, bd, out);
    } else {
        unsigned short* seqh = (unsigned short*)d_ws;
        gclstm_main<0><<<dim3(1024), dim3(TPB), 55808, stream>>>(
            src, tgt, We, be, Wxl, bxl, Wxr, Whl, bhl, Whr, wg, bg, nullptr, seqh);
        gclstm_proj<0><<<dim3(768), dim3(192), 52480, stream>>>(nullptr, seqh, Wd, bd, out);
    }
}